// Round 18
// baseline (134.555 us; speedup 1.0000x reference)
//
#include <hip/hip_runtime.h>
#include <math.h>

// Shapes fixed by setup_inputs(): B=8, N=8192, M=512 clusters, S=64 samples.
#define BB 8
#define NN 8192
#define MM 512
#define SS 64
#define NCLUST (BB*MM)                 // 4096

// d_out layout (flat, return order, all read back as f32):
// new_xyz[8*512*3] | idx(as float)[8*512*64] | attention[8*512] | orientation[8*512]
#define OUT_IDX   (BB*MM*3)            // 12288
#define OUT_ATT   (OUT_IDX + BB*MM*SS) // 274432
#define OUT_ORI   (OUT_ATT + BB*MM)    // 278528

// d_ws layout (ushorts): [0,8192) W2 B-frags | [8192,40960) W3 B-frags.
#define WS_W3 8192

typedef short v8s __attribute__((ext_vector_type(8)));   // 8 bf16 (MFMA A/B frag)
typedef float v4f __attribute__((ext_vector_type(4)));   // MFMA C/D frag

static __device__ __forceinline__ unsigned short f2bf(float x) {
    unsigned int u = __float_as_uint(x);
    u += 0x7FFFu + ((u >> 16) & 1u);     // round-to-nearest-even
    return (unsigned short)(u >> 16);
}

// ---- Kernel 0: pack W2 (64x128) and W3 (128x256) fp32 -> bf16 MFMA B-frag
// layout. B-frag lane l holds B[kt*32+(l>>4)*8+j][nt*16+(l&15)], j=0..7,
// stored contiguous (16 B/lane) so the main kernel loads one dwordx4/frag.
__global__ void pack_weights(const float* __restrict__ W2,
                             const float* __restrict__ W3,
                             unsigned short* __restrict__ ws)
{
    const int gid = blockIdx.x * 256 + threadIdx.x;    // 0..5119
    const float* W; unsigned short* dst; int N, kt, nt, lane;
    if (gid < 1024) {                   // W2: 16 tiles * 64 lanes
        W = W2; N = 128;
        const int tile = gid >> 6; lane = gid & 63;
        kt = tile >> 3; nt = tile & 7;
        dst = ws + (size_t)(tile * 64 + lane) * 8;
    } else {                            // W3: 64 tiles * 64 lanes
        const int g = gid - 1024;
        W = W3; N = 256;
        const int tile = g >> 6; lane = g & 63;
        kt = tile >> 4; nt = tile & 15;
        dst = ws + WS_W3 + (size_t)(tile * 64 + lane) * 8;
    }
    const int k0 = kt * 32 + (lane >> 4) * 8;
    const int n  = nt * 16 + (lane & 15);
    union { unsigned short u[8]; v8s v; } f;
    #pragma unroll
    for (int j = 0; j < 8; ++j) f.u[j] = f2bf(W[(k0 + j) * N + n]);
    *(v8s*)dst = f.v;
}

// ---- Fused kernel (exact R8 revert = best measured: 57.2us fused, 132.8us
// total). R14's pad-free clamp + setprio deltas measured 59.3us fused
// (slightly WORSE) and are stripped. Session plateau note: 7 structural
// variants (CPB loop, LDS compaction, stripe BQ, joint 2-cluster, setprio,
// pad-free) all land 57-66us with Occ~33%, MfmaUtil~15%, HBM<1% — a
// latency floor at ~10.8 waves/CU this structure does not move. ----
__global__ __launch_bounds__(256, 4) void feat3d_fused(
    const float* __restrict__ xyz,
    const float* __restrict__ W1, const float* __restrict__ b1,
    const float* __restrict__ b2, const float* __restrict__ b3,
    const unsigned short* __restrict__ Wp,
    const float* __restrict__ W4, const float* __restrict__ b4,
    const float* __restrict__ W5, const float* __restrict__ b5,
    const float* __restrict__ Wa, const float* __restrict__ ba,
    const float* __restrict__ Wo, const float* __restrict__ bo,
    float* __restrict__ out)
{
    // LDS map (front): [0,8192) a2p | [8192,24576) a3p.
    //   smallf/ls_idx/ls_mask alias a3p[0..2368): all dead before the L2
    //   epilogue writes a3p (ls_g/ls_w1 last read in L1; ls_idx last read at
    //   the idx store; ls_mask last read in BQ — all before the L1-end sync).
    // LDS map (tail, aliases a2p): vbuf 1K | h4part 4K | h4f 512B | h5p 1K.
    __shared__ __align__(16) unsigned char lds[24576];
    unsigned short* a2p = (unsigned short*)lds;            // h1 A-frags, 8 KB
    unsigned short* a3p = (unsigned short*)(lds + 8192);   // h2 A-frags, 16 KB
    float* smallf       = (float*)(lds + 8192);            // 512 f32: g | w1
    int* ls_idx         = (int*)(lds + 10240);             // 64
    unsigned long long* ls_mask = (unsigned long long*)(lds + 10496); // [2][4]

    float* ls_g  = smallf;         // [64][4]
    float* ls_w1 = smallf + 256;   // [64][4]

    // Epilogue scratch aliases a2p (dead after the L2 MFMA reads, fenced by
    // the pre-L3 __syncthreads):
    float* vbuf   = (float*)lds;            // 256 f32 pooled v (fp32)
    float* h4part = (float*)(lds + 1024);   // [8][128] f32 k-partials
    float* h4f    = (float*)(lds + 5120);   // 128 f32
    float* h5p    = (float*)(lds + 5632);   // [4][64] f32

    const int t   = threadIdx.x;
    const int wv  = t >> 6;
    const int l   = t & 63;
    const int q   = l >> 4;
    const int r16 = l & 15;
    const int blk = blockIdx.x;
    const int b   = blk >> 9;
    const int m   = blk & 511;
    const float* xb = xyz + (size_t)b * (NN * 3);

    // Prefetch W2 B-frags NOW (packed, one dwordx4 each); they stay in flight
    // through the ball query (reg loads aren't drained by __syncthreads).
    const v8s* W2f = (const v8s*)Wp;
    v8s bfr[2][2];
    #pragma unroll
    for (int kt = 0; kt < 2; ++kt)
        #pragma unroll
        for (int ni = 0; ni < 2; ++ni)
            bfr[kt][ni] = W2f[(kt*8 + 2*wv + ni)*64 + l];

    const float cx = xb[m*3+0], cy = xb[m*3+1], cz = xb[m*3+2];

    if (t < 3) out[(b*MM + m)*3 + t] = xb[m*3 + t];   // new_xyz

    // Stage W1^T + b1 early (overlaps BQ latency).
    if (t < 64) {
        ls_w1[t*4+0] = W1[t];
        ls_w1[t*4+1] = W1[64 + t];
        ls_w1[t*4+2] = W1[128 + t];
        ls_w1[t*4+3] = b1[t];
    }

    // ---- Ball query with fused gather (256 pts/iter): first 64 idx with
    // d2 < 4.0 (by index); valid lane already holds dx,dy,dz so g is written
    // during the scan. Pads copy slot 0 (= globally first valid). ----
    int cnt = 0;
    {
        int base = 0, pb = 0;
        while (base < NN && cnt < SS) {
            const int j = base + t;
            const float dx = xb[j*3+0] - cx;
            const float dy = xb[j*3+1] - cy;
            const float dz = xb[j*3+2] - cz;
            // no fma contraction: idx must be exact at the d2==4.0 boundary
            const float d2 = __fadd_rn(__fadd_rn(__fmul_rn(dx,dx), __fmul_rn(dy,dy)),
                                       __fmul_rn(dz,dz));
            const bool valid = d2 < 4.0f;
            const unsigned long long mask = __ballot(valid);
            if (l == 0) ls_mask[pb*4 + wv] = mask;
            __syncthreads();
            const unsigned long long m0 = ls_mask[pb*4+0], m1 = ls_mask[pb*4+1],
                                     m2 = ls_mask[pb*4+2], m3 = ls_mask[pb*4+3];
            int below = __popcll(mask & ((1ull << l) - 1ull));
            if (wv > 0) below += (int)__popcll(m0);
            if (wv > 1) below += (int)__popcll(m1);
            if (wv > 2) below += (int)__popcll(m2);
            const int pos = cnt + below;
            if (valid && pos < SS) {
                ls_idx[pos]   = j;
                ls_g[pos*4+0] = dx * 0.5f;
                ls_g[pos*4+1] = dy * 0.5f;
                ls_g[pos*4+2] = dz * 0.5f;
            }
            cnt += (int)(__popcll(m0) + __popcll(m1) + __popcll(m2) + __popcll(m3));
            if (cnt > SS) cnt = SS;
            base += 256;
            pb ^= 1;               // double-buffered masks
        }
    }
    __syncthreads();
    if (t < SS && t >= cnt) {      // pad with first neighbor (slot 0)
        ls_idx[t]   = ls_idx[0];
        ls_g[t*4+0] = ls_g[0];
        ls_g[t*4+1] = ls_g[1];
        ls_g[t*4+2] = ls_g[2];
    }
    __syncthreads();
    if (t < 64) out[OUT_IDX + (b*MM + m)*SS + t] = (float)ls_idx[t];

    // ---- L1 (fp32) + pack h1 into A-frag layout:
    // lane l of wave wv produces s = wv*16+r16, c = kt*32+q*8+j ----
    {
        const int s = wv*16 + r16;
        const float4 g4 = *(const float4*)&ls_g[s*4];
        #pragma unroll
        for (int kt = 0; kt < 2; ++kt) {
            union { unsigned short u[8]; v8s v; } fr;
            #pragma unroll
            for (int j = 0; j < 8; ++j) {
                const int c = kt*32 + q*8 + j;
                const float4 w = *(const float4*)&ls_w1[c*4];
                const float h = fmaf(g4.x, w.x, fmaf(g4.y, w.y, fmaf(g4.z, w.z, w.w)));
                fr.u[j] = f2bf(fmaxf(h, 0.f));
            }
            *(v8s*)&a2p[((kt*4 + wv)*64 + l)*8] = fr.v;
        }
    }
    __syncthreads();

    // ---- L2 MFMA: h2 = relu(h1 @ W2 + b2). Wave wv owns nt {2wv, 2wv+1}. ----
    {
        const v4f z = {0.f, 0.f, 0.f, 0.f};
        v4f acc[4][2];
        #pragma unroll
        for (int mt = 0; mt < 4; ++mt) { acc[mt][0] = z; acc[mt][1] = z; }

        #pragma unroll
        for (int kt = 0; kt < 2; ++kt)
            #pragma unroll
            for (int mt = 0; mt < 4; ++mt) {
                const v8s a = *(const v8s*)&a2p[((kt*4 + mt)*64 + l)*8];
                #pragma unroll
                for (int ni = 0; ni < 2; ++ni)
                    acc[mt][ni] = __builtin_amdgcn_mfma_f32_16x16x32_bf16(
                        a, bfr[kt][ni], acc[mt][ni], 0, 0, 0);
            }

        // Epilogue: +b2, relu, bf16, scatter into L3 A-frag layout.
        // C/D elem (mt,ni,rg): s = mt*16+q*4+rg, c2 = (2wv+ni)*16+r16.
        #pragma unroll
        for (int ni = 0; ni < 2; ++ni) {
            const int c2  = (2*wv + ni)*16 + r16;
            const float bias = b2[c2];
            const int kt3 = c2 >> 5;
            const int lhi = ((c2 >> 3) & 3) << 4;
            const int j3  = c2 & 7;
            #pragma unroll
            for (int mt = 0; mt < 4; ++mt)
                #pragma unroll
                for (int rg = 0; rg < 4; ++rg) {
                    const float h = fmaxf(acc[mt][ni][rg] + bias, 0.f);
                    const int s15 = q*4 + rg;
                    a3p[((kt3*4 + mt)*64 + (lhi | s15))*8 + j3] = f2bf(h);
                }
        }
    }
    __syncthreads();

    // ---- L3 MFMA in 2 passes (acc[4][2] keeps regs <=128).
    // Wave wv owns nt {4wv..4wv+3}; pass np covers nt0=4wv+2np, nt0+1.
    // B-frags software-pipelined one kt ahead. Pool in regs -> vbuf (fp32). ----
    {
        const v8s* W3f = (const v8s*)(Wp + WS_W3);

        #pragma unroll
        for (int np = 0; np < 2; ++np) {
            const int nt0 = 4*wv + 2*np;
            const v4f z = {0.f, 0.f, 0.f, 0.f};
            v4f acc[4][2];
            #pragma unroll
            for (int mt = 0; mt < 4; ++mt) { acc[mt][0] = z; acc[mt][1] = z; }

            v8s bb0 = W3f[(0*16 + nt0    )*64 + l];
            v8s bb1 = W3f[(0*16 + nt0 + 1)*64 + l];
            #pragma unroll
            for (int kt = 0; kt < 4; ++kt) {
                v8s a[4];
                #pragma unroll
                for (int mt = 0; mt < 4; ++mt)
                    a[mt] = *(const v8s*)&a3p[((kt*4 + mt)*64 + l)*8];
                v8s nb0, nb1;
                if (kt < 3) {
                    nb0 = W3f[((kt+1)*16 + nt0    )*64 + l];
                    nb1 = W3f[((kt+1)*16 + nt0 + 1)*64 + l];
                }
                #pragma unroll
                for (int mt = 0; mt < 4; ++mt) {
                    acc[mt][0] = __builtin_amdgcn_mfma_f32_16x16x32_bf16(
                        a[mt], bb0, acc[mt][0], 0, 0, 0);
                    acc[mt][1] = __builtin_amdgcn_mfma_f32_16x16x32_bf16(
                        a[mt], bb1, acc[mt][1], 0, 0, 0);
                }
                if (kt < 3) { bb0 = nb0; bb1 = nb1; }
            }

            // Pool over s (16 regs + cross-quad shfl); bias+relu after pool
            // (relu monotone, bias per-column => commutes). Keep v in fp32 LDS.
            #pragma unroll
            for (int ni = 0; ni < 2; ++ni) {
                float mx = acc[0][ni][0];
                #pragma unroll
                for (int mt = 0; mt < 4; ++mt)
                    #pragma unroll
                    for (int rg = 0; rg < 4; ++rg)
                        mx = fmaxf(mx, acc[mt][ni][rg]);
                mx = fmaxf(mx, __shfl_xor(mx, 16));
                mx = fmaxf(mx, __shfl_xor(mx, 32));
                if (q == 0) {
                    const int c = (nt0 + ni)*16 + r16;
                    vbuf[c] = fmaxf(mx + b3[c], 0.f);
                }
            }
        }
    }
    __syncthreads();   // vbuf[256] complete

    // ---- L4 (fp32): h4[c] = b4[c] + sum_k v[k] W4[k][c].
    // thread = (col-group cgp = t&31 -> 4 cols, k-part kp = t>>5 -> 32 k).
    // float4 row loads (coalesced), 4 fma/load, named acc (no arrays). ----
    {
        const int cgp = t & 31;
        const int kp  = t >> 5;
        const float4* W4v = (const float4*)W4;   // row-major [256][32] float4
        float4 acc = make_float4(0.f, 0.f, 0.f, 0.f);
        const int kbase = kp * 32;
        #pragma unroll 4
        for (int kk = 0; kk < 32; ++kk) {
            const int k = kbase + kk;
            const float4 w = W4v[k*32 + cgp];
            const float vv = vbuf[k];
            acc.x = fmaf(vv, w.x, acc.x);
            acc.y = fmaf(vv, w.y, acc.y);
            acc.z = fmaf(vv, w.z, acc.z);
            acc.w = fmaf(vv, w.w, acc.w);
        }
        *(float4*)&h4part[kp*128 + cgp*4] = acc;
    }
    __syncthreads();
    if (t < 128) {     // reduce 8 k-partials (+b4)
        float s = b4[t];
        #pragma unroll
        for (int kp = 0; kp < 8; ++kp) s += h4part[kp*128 + t];
        h4f[t] = s;
    }
    __syncthreads();

    // ---- L5 (fp32): h5[c] = b5[c] + sum_k h4[k] W5[k][c].
    // thread = (c = t&63, k-quarter = t>>6). ----
    {
        const int c5 = t & 63;
        const int kq = t >> 6;
        const float* W5c = W5 + c5;
        float acc = 0.f;
        for (int k = kq*32; k < kq*32 + 32; k += 4) {
            const float4 hh = *(const float4*)&h4f[k];
            acc = fmaf(hh.x, W5c[(k+0)*64],
                  fmaf(hh.y, W5c[(k+1)*64],
                  fmaf(hh.z, W5c[(k+2)*64],
                  fmaf(hh.w, W5c[(k+3)*64], acc))));
        }
        h5p[t] = acc;            // t == kq*64 + c5
    }
    __syncthreads();

    // ---- Heads (wave 0): attention = softplus(h5.Wa+ba);
    // orientation = atan2(o1,o0) (normalization is scale-invariant -> skipped). ----
    if (t < 64) {
        const float h5v = h5p[t] + h5p[64 + t] + h5p[128 + t] + h5p[192 + t] + b5[t];
        float va = h5v * Wa[t];
        float v0 = h5v * Wo[2*t + 0];
        float v1 = h5v * Wo[2*t + 1];
        #pragma unroll
        for (int off = 32; off > 0; off >>= 1) {
            va += __shfl_down(va, off);
            v0 += __shfl_down(v0, off);
            v1 += __shfl_down(v1, off);
        }
        if (t == 0) {
            const float a = va + ba[0];
            out[OUT_ATT + blk] = fmaxf(a, 0.f) + log1pf(expf(-fabsf(a)));
            out[OUT_ORI + blk] = atan2f(v1 + bo[1], v0 + bo[0]);
        }
    }
}

extern "C" void kernel_launch(void* const* d_in, const int* in_sizes, int n_in,
                              void* d_out, int out_size, void* d_ws, size_t ws_size,
                              hipStream_t stream) {
    const float* xyz = (const float*)d_in[0];
    const float* W1  = (const float*)d_in[1];
    const float* b1  = (const float*)d_in[2];
    const float* W2  = (const float*)d_in[3];
    const float* b2  = (const float*)d_in[4];
    const float* W3  = (const float*)d_in[5];
    const float* b3  = (const float*)d_in[6];
    const float* W4  = (const float*)d_in[7];
    const float* b4  = (const float*)d_in[8];
    const float* W5  = (const float*)d_in[9];
    const float* b5  = (const float*)d_in[10];
    const float* Wa  = (const float*)d_in[11];
    const float* ba  = (const float*)d_in[12];
    const float* Wo  = (const float*)d_in[13];
    const float* bo  = (const float*)d_in[14];

    unsigned short* ws = (unsigned short*)d_ws;

    pack_weights<<<dim3(20), dim3(256), 0, stream>>>(W2, W3, ws);
    feat3d_fused<<<dim3(NCLUST), dim3(256), 0, stream>>>(
        xyz, W1, b1, b2, b3, ws, W4, b4, W5, b5, Wa, ba, Wo, bo, (float*)d_out);
}

// Round 20
// 130.887 us; speedup vs baseline: 1.0280x; 1.0280x over previous
//
#include <hip/hip_runtime.h>
#include <math.h>

// Shapes fixed by setup_inputs(): B=8, N=8192, M=512 clusters, S=64 samples.
#define BB 8
#define NN 8192
#define MM 512
#define SS 64
#define NCLUST (BB*MM)                 // 4096
#define TCL 4                          // clusters per tail block

// d_out layout (flat, return order, all read back as f32):
// new_xyz[8*512*3] | idx(as float)[8*512*64] | attention[8*512] | orientation[8*512]
#define OUT_IDX   (BB*MM*3)            // 12288
#define OUT_ATT   (OUT_IDX + BB*MM*SS) // 274432
#define OUT_ORI   (OUT_ATT + BB*MM)    // 278528

// d_ws layout (ushorts): [0,8192) W2 B-frags | [8192,40960) W3 B-frags |
// [40960, 40960+4096*256) pooled v (bf16). ~2.08 MB (R0-proven size).
#define WS_W3 8192
#define WS_V  40960

typedef short v8s __attribute__((ext_vector_type(8)));   // 8 bf16 (MFMA A/B frag)
typedef float v4f __attribute__((ext_vector_type(4)));   // MFMA C/D frag

static __device__ __forceinline__ unsigned short f2bf(float x) {
    unsigned int u = __float_as_uint(x);
    u += 0x7FFFu + ((u >> 16) & 1u);     // round-to-nearest-even
    return (unsigned short)(u >> 16);
}

// ---- Kernel 0: pack W2 (64x128) and W3 (128x256) fp32 -> bf16 MFMA B-frag
// layout. B-frag lane l holds B[kt*32+(l>>4)*8+j][nt*16+(l&15)], j=0..7,
// stored contiguous (16 B/lane) so the main kernel loads one dwordx4/frag.
__global__ void pack_weights(const float* __restrict__ W2,
                             const float* __restrict__ W3,
                             unsigned short* __restrict__ ws)
{
    const int gid = blockIdx.x * 256 + threadIdx.x;    // 0..5119
    const float* W; unsigned short* dst; int N, kt, nt, lane;
    if (gid < 1024) {                   // W2: 16 tiles * 64 lanes
        W = W2; N = 128;
        const int tile = gid >> 6; lane = gid & 63;
        kt = tile >> 3; nt = tile & 7;
        dst = ws + (size_t)(tile * 64 + lane) * 8;
    } else {                            // W3: 64 tiles * 64 lanes
        const int g = gid - 1024;
        W = W3; N = 256;
        const int tile = g >> 6; lane = g & 63;
        kt = tile >> 4; nt = tile & 15;
        dst = ws + WS_W3 + (size_t)(tile * 64 + lane) * 8;
    }
    const int k0 = kt * 32 + (lane >> 4) * 8;
    const int n  = nt * 16 + (lane & 15);
    union { unsigned short u[8]; v8s v; } f;
    #pragma unroll
    for (int j = 0; j < 8; ++j) f.u[j] = f2bf(W[(k0 + j) * N + n]);
    *(v8s*)dst = f.v;
}

// ---- Front: R8 structure minus the L4/L5/heads epilogue (~10-13us of
// phases + 4 barriers). Pool writes v (bf16) straight to workspace.
// R18 theory: each fused block streamed W4+W5 = 160 KB from L2 (~2900
// cyc/block, 656 MB total); the 4-cluster tail amortizes that 4x while
// keeping front parallelism at 4096 blocks. ----
__global__ __launch_bounds__(256, 4) void feat3d_front(
    const float* __restrict__ xyz,
    const float* __restrict__ W1, const float* __restrict__ b1,
    const float* __restrict__ b2, const float* __restrict__ b3,
    const unsigned short* __restrict__ Wp,
    unsigned short* __restrict__ vdst,
    float* __restrict__ out)
{
    // LDS map: [0,8192) a2p | [8192,24576) a3p.
    //   smallf/ls_idx/ls_mask alias a3p[0..2368): all dead before the L2
    //   epilogue writes a3p (last reads happen before the L1-end sync).
    __shared__ __align__(16) unsigned char lds[24576];
    unsigned short* a2p = (unsigned short*)lds;            // h1 A-frags, 8 KB
    unsigned short* a3p = (unsigned short*)(lds + 8192);   // h2 A-frags, 16 KB
    float* smallf       = (float*)(lds + 8192);            // 512 f32: g | w1
    int* ls_idx         = (int*)(lds + 10240);             // 64
    unsigned long long* ls_mask = (unsigned long long*)(lds + 10496); // [2][4]

    float* ls_g  = smallf;         // [64][4]
    float* ls_w1 = smallf + 256;   // [64][4]

    const int t   = threadIdx.x;
    const int wv  = t >> 6;
    const int l   = t & 63;
    const int q   = l >> 4;
    const int r16 = l & 15;
    const int blk = blockIdx.x;
    const int b   = blk >> 9;
    const int m   = blk & 511;
    const float* xb = xyz + (size_t)b * (NN * 3);

    // Prefetch W2 B-frags NOW (packed, one dwordx4 each); they stay in flight
    // through the ball query (reg loads aren't drained by __syncthreads).
    const v8s* W2f = (const v8s*)Wp;
    v8s bfr[2][2];
    #pragma unroll
    for (int kt = 0; kt < 2; ++kt)
        #pragma unroll
        for (int ni = 0; ni < 2; ++ni)
            bfr[kt][ni] = W2f[(kt*8 + 2*wv + ni)*64 + l];

    const float cx = xb[m*3+0], cy = xb[m*3+1], cz = xb[m*3+2];

    if (t < 3) out[(b*MM + m)*3 + t] = xb[m*3 + t];   // new_xyz

    // Stage W1^T + b1 early (overlaps BQ latency).
    if (t < 64) {
        ls_w1[t*4+0] = W1[t];
        ls_w1[t*4+1] = W1[64 + t];
        ls_w1[t*4+2] = W1[128 + t];
        ls_w1[t*4+3] = b1[t];
    }

    // ---- Ball query with fused gather (256 pts/iter): first 64 idx with
    // d2 < 4.0 (by index); valid lane already holds dx,dy,dz so g is written
    // during the scan. Pads copy slot 0 (= globally first valid). ----
    int cnt = 0;
    {
        int base = 0, pb = 0;
        while (base < NN && cnt < SS) {
            const int j = base + t;
            const float dx = xb[j*3+0] - cx;
            const float dy = xb[j*3+1] - cy;
            const float dz = xb[j*3+2] - cz;
            // no fma contraction: idx must be exact at the d2==4.0 boundary
            const float d2 = __fadd_rn(__fadd_rn(__fmul_rn(dx,dx), __fmul_rn(dy,dy)),
                                       __fmul_rn(dz,dz));
            const bool valid = d2 < 4.0f;
            const unsigned long long mask = __ballot(valid);
            if (l == 0) ls_mask[pb*4 + wv] = mask;
            __syncthreads();
            const unsigned long long m0 = ls_mask[pb*4+0], m1 = ls_mask[pb*4+1],
                                     m2 = ls_mask[pb*4+2], m3 = ls_mask[pb*4+3];
            int below = __popcll(mask & ((1ull << l) - 1ull));
            if (wv > 0) below += (int)__popcll(m0);
            if (wv > 1) below += (int)__popcll(m1);
            if (wv > 2) below += (int)__popcll(m2);
            const int pos = cnt + below;
            if (valid && pos < SS) {
                ls_idx[pos]   = j;
                ls_g[pos*4+0] = dx * 0.5f;
                ls_g[pos*4+1] = dy * 0.5f;
                ls_g[pos*4+2] = dz * 0.5f;
            }
            cnt += (int)(__popcll(m0) + __popcll(m1) + __popcll(m2) + __popcll(m3));
            if (cnt > SS) cnt = SS;
            base += 256;
            pb ^= 1;               // double-buffered masks
        }
    }
    __syncthreads();
    if (t < SS && t >= cnt) {      // pad with first neighbor (slot 0)
        ls_idx[t]   = ls_idx[0];
        ls_g[t*4+0] = ls_g[0];
        ls_g[t*4+1] = ls_g[1];
        ls_g[t*4+2] = ls_g[2];
    }
    __syncthreads();
    if (t < 64) out[OUT_IDX + (b*MM + m)*SS + t] = (float)ls_idx[t];

    // ---- L1 (fp32) + pack h1 into A-frag layout:
    // lane l of wave wv produces s = wv*16+r16, c = kt*32+q*8+j ----
    {
        const int s = wv*16 + r16;
        const float4 g4 = *(const float4*)&ls_g[s*4];
        #pragma unroll
        for (int kt = 0; kt < 2; ++kt) {
            union { unsigned short u[8]; v8s v; } fr;
            #pragma unroll
            for (int j = 0; j < 8; ++j) {
                const int c = kt*32 + q*8 + j;
                const float4 w = *(const float4*)&ls_w1[c*4];
                const float h = fmaf(g4.x, w.x, fmaf(g4.y, w.y, fmaf(g4.z, w.z, w.w)));
                fr.u[j] = f2bf(fmaxf(h, 0.f));
            }
            *(v8s*)&a2p[((kt*4 + wv)*64 + l)*8] = fr.v;
        }
    }
    __syncthreads();

    // ---- L2 MFMA: h2 = relu(h1 @ W2 + b2). Wave wv owns nt {2wv, 2wv+1}. ----
    {
        const v4f z = {0.f, 0.f, 0.f, 0.f};
        v4f acc[4][2];
        #pragma unroll
        for (int mt = 0; mt < 4; ++mt) { acc[mt][0] = z; acc[mt][1] = z; }

        #pragma unroll
        for (int kt = 0; kt < 2; ++kt)
            #pragma unroll
            for (int mt = 0; mt < 4; ++mt) {
                const v8s a = *(const v8s*)&a2p[((kt*4 + mt)*64 + l)*8];
                #pragma unroll
                for (int ni = 0; ni < 2; ++ni)
                    acc[mt][ni] = __builtin_amdgcn_mfma_f32_16x16x32_bf16(
                        a, bfr[kt][ni], acc[mt][ni], 0, 0, 0);
            }

        // Epilogue: +b2, relu, bf16, scatter into L3 A-frag layout.
        // C/D elem (mt,ni,rg): s = mt*16+q*4+rg, c2 = (2wv+ni)*16+r16.
        #pragma unroll
        for (int ni = 0; ni < 2; ++ni) {
            const int c2  = (2*wv + ni)*16 + r16;
            const float bias = b2[c2];
            const int kt3 = c2 >> 5;
            const int lhi = ((c2 >> 3) & 3) << 4;
            const int j3  = c2 & 7;
            #pragma unroll
            for (int mt = 0; mt < 4; ++mt)
                #pragma unroll
                for (int rg = 0; rg < 4; ++rg) {
                    const float h = fmaxf(acc[mt][ni][rg] + bias, 0.f);
                    const int s15 = q*4 + rg;
                    a3p[((kt3*4 + mt)*64 + (lhi | s15))*8 + j3] = f2bf(h);
                }
        }
    }
    __syncthreads();

    // ---- L3 MFMA in 2 passes; pool in regs; v -> global bf16 (R0 path). ----
    {
        const v8s* W3f = (const v8s*)(Wp + WS_W3);
        unsigned short* vrow = vdst + (size_t)blk * 256;

        #pragma unroll
        for (int np = 0; np < 2; ++np) {
            const int nt0 = 4*wv + 2*np;
            const v4f z = {0.f, 0.f, 0.f, 0.f};
            v4f acc[4][2];
            #pragma unroll
            for (int mt = 0; mt < 4; ++mt) { acc[mt][0] = z; acc[mt][1] = z; }

            v8s bb0 = W3f[(0*16 + nt0    )*64 + l];
            v8s bb1 = W3f[(0*16 + nt0 + 1)*64 + l];
            #pragma unroll
            for (int kt = 0; kt < 4; ++kt) {
                v8s a[4];
                #pragma unroll
                for (int mt = 0; mt < 4; ++mt)
                    a[mt] = *(const v8s*)&a3p[((kt*4 + mt)*64 + l)*8];
                v8s nb0, nb1;
                if (kt < 3) {
                    nb0 = W3f[((kt+1)*16 + nt0    )*64 + l];
                    nb1 = W3f[((kt+1)*16 + nt0 + 1)*64 + l];
                }
                #pragma unroll
                for (int mt = 0; mt < 4; ++mt) {
                    acc[mt][0] = __builtin_amdgcn_mfma_f32_16x16x32_bf16(
                        a[mt], bb0, acc[mt][0], 0, 0, 0);
                    acc[mt][1] = __builtin_amdgcn_mfma_f32_16x16x32_bf16(
                        a[mt], bb1, acc[mt][1], 0, 0, 0);
                }
                if (kt < 3) { bb0 = nb0; bb1 = nb1; }
            }

            // Pool over s (16 regs + cross-quad shfl); bias+relu after pool
            // (relu monotone, bias per-column => commutes). Store bf16 v.
            #pragma unroll
            for (int ni = 0; ni < 2; ++ni) {
                float mx = acc[0][ni][0];
                #pragma unroll
                for (int mt = 0; mt < 4; ++mt)
                    #pragma unroll
                    for (int rg = 0; rg < 4; ++rg)
                        mx = fmaxf(mx, acc[mt][ni][rg]);
                mx = fmaxf(mx, __shfl_xor(mx, 16));
                mx = fmaxf(mx, __shfl_xor(mx, 32));
                if (q == 0) {
                    const int c = (nt0 + ni)*16 + r16;
                    vrow[c] = f2bf(fmaxf(mx + b3[c], 0.f));
                }
            }
        }
    }
}

// ---- Tail: 4 clusters/block, grid 1024 (= 4 blocks/CU — vs R0's 16cl/256blk
// at 1 block/CU which was latency-exposed). W4/W5 streamed once per block,
// 16 fma per loaded W4 float4. Straight-line, named accs (no scratch risk). ----
__global__ __launch_bounds__(256) void feat3d_tail(
    const unsigned short* __restrict__ vsrc,
    const float* __restrict__ W4, const float* __restrict__ b4,
    const float* __restrict__ W5, const float* __restrict__ b5,
    const float* __restrict__ Wa, const float* __restrict__ ba,
    const float* __restrict__ Wo, const float* __restrict__ bo,
    float* __restrict__ out)
{
    __shared__ __align__(16) float V[TCL*256];        // 4 KB (flat [cl*256+k])
    __shared__ __align__(16) float h4part[8][TCL*128];// 16 KB
    __shared__ __align__(16) float h4f[TCL*128];      // 2 KB
    __shared__ __align__(16) float h5p[4][TCL*64];    // 4 KB

    const int t   = threadIdx.x;
    const int cl0 = blockIdx.x * TCL;

    // Load v tile (bf16 -> f32): 2048 bf16 = 4 KB; one uint4 (8 bf16)/thread.
    {
        const uint4 r = ((const uint4*)(vsrc + (size_t)cl0 * 256))[t];
        const unsigned int u[4] = {r.x, r.y, r.z, r.w};
        #pragma unroll
        for (int j = 0; j < 4; ++j) {
            V[t*8 + 2*j]     = __uint_as_float(u[j] << 16);
            V[t*8 + 2*j + 1] = __uint_as_float(u[j] & 0xFFFF0000u);
        }
    }
    __syncthreads();

    // L4: thread = (cgp = t&31 -> 4 cols, kp = t>>5 -> 32 ks). W4 float4
    // loaded once, fma'd into 4 named cluster accs (16 fma/load).
    {
        const int cgp = t & 31;
        const int kp  = t >> 5;
        const float4* W4v = (const float4*)W4;   // row-major [256][32] float4
        float4 a0 = make_float4(0.f,0.f,0.f,0.f);
        float4 a1 = make_float4(0.f,0.f,0.f,0.f);
        float4 a2 = make_float4(0.f,0.f,0.f,0.f);
        float4 a3 = make_float4(0.f,0.f,0.f,0.f);
        const int kbase = kp * 32;
        #pragma unroll 4
        for (int kk = 0; kk < 32; ++kk) {
            const int k = kbase + kk;
            const float4 w = W4v[k*32 + cgp];
            const float v0 = V[0*256 + k];
            const float v1 = V[1*256 + k];
            const float v2 = V[2*256 + k];
            const float v3 = V[3*256 + k];
            a0.x = fmaf(v0, w.x, a0.x); a0.y = fmaf(v0, w.y, a0.y);
            a0.z = fmaf(v0, w.z, a0.z); a0.w = fmaf(v0, w.w, a0.w);
            a1.x = fmaf(v1, w.x, a1.x); a1.y = fmaf(v1, w.y, a1.y);
            a1.z = fmaf(v1, w.z, a1.z); a1.w = fmaf(v1, w.w, a1.w);
            a2.x = fmaf(v2, w.x, a2.x); a2.y = fmaf(v2, w.y, a2.y);
            a2.z = fmaf(v2, w.z, a2.z); a2.w = fmaf(v2, w.w, a2.w);
            a3.x = fmaf(v3, w.x, a3.x); a3.y = fmaf(v3, w.y, a3.y);
            a3.z = fmaf(v3, w.z, a3.z); a3.w = fmaf(v3, w.w, a3.w);
        }
        *(float4*)&h4part[kp][0*128 + cgp*4] = a0;
        *(float4*)&h4part[kp][1*128 + cgp*4] = a1;
        *(float4*)&h4part[kp][2*128 + cgp*4] = a2;
        *(float4*)&h4part[kp][3*128 + cgp*4] = a3;
    }
    __syncthreads();

    // Reduce 8 k-partials -> h4f[cl*128+c] (+b4). 512 outputs, 2/thread.
    #pragma unroll
    for (int idx = t; idx < TCL*128; idx += 256) {
        const int c = idx & 127;
        float s = b4[c];
        #pragma unroll
        for (int kp = 0; kp < 8; ++kp) s += h4part[kp][idx];
        h4f[idx] = s;
    }
    __syncthreads();

    // L5: thread = (c5 = t&63, kq = t>>6); W5 loaded once, 4 named accs.
    {
        const int c5 = t & 63;
        const int kq = t >> 6;
        float s0 = 0.f, s1 = 0.f, s2 = 0.f, s3 = 0.f;
        #pragma unroll 4
        for (int kk = 0; kk < 32; ++kk) {
            const int k = kq*32 + kk;
            const float w = W5[k*64 + c5];
            s0 = fmaf(h4f[0*128 + k], w, s0);
            s1 = fmaf(h4f[1*128 + k], w, s1);
            s2 = fmaf(h4f[2*128 + k], w, s2);
            s3 = fmaf(h4f[3*128 + k], w, s3);
        }
        h5p[kq][0*64 + c5] = s0;
        h5p[kq][1*64 + c5] = s1;
        h5p[kq][2*64 + c5] = s2;
        h5p[kq][3*64 + c5] = s3;
    }
    __syncthreads();

    // Heads: wave wv owns cluster wv. attention = softplus(h5.Wa+ba);
    // orientation = atan2(o1,o0) (normalization scale-invariant -> skipped).
    {
        const int wv = t >> 6, l = t & 63;
        float h5v = b5[l];
        #pragma unroll
        for (int kq = 0; kq < 4; ++kq) h5v += h5p[kq][wv*64 + l];
        float va = h5v * Wa[l];
        float v0 = h5v * Wo[2*l + 0];
        float v1 = h5v * Wo[2*l + 1];
        #pragma unroll
        for (int off = 32; off > 0; off >>= 1) {
            va += __shfl_down(va, off);
            v0 += __shfl_down(v0, off);
            v1 += __shfl_down(v1, off);
        }
        if (l == 0) {
            const int cg = cl0 + wv;
            const float a = va + ba[0];
            out[OUT_ATT + cg] = fmaxf(a, 0.f) + log1pf(expf(-fabsf(a)));
            out[OUT_ORI + cg] = atan2f(v1 + bo[1], v0 + bo[0]);
        }
    }
}

extern "C" void kernel_launch(void* const* d_in, const int* in_sizes, int n_in,
                              void* d_out, int out_size, void* d_ws, size_t ws_size,
                              hipStream_t stream) {
    const float* xyz = (const float*)d_in[0];
    const float* W1  = (const float*)d_in[1];
    const float* b1  = (const float*)d_in[2];
    const float* W2  = (const float*)d_in[3];
    const float* b2  = (const float*)d_in[4];
    const float* W3  = (const float*)d_in[5];
    const float* b3  = (const float*)d_in[6];
    const float* W4  = (const float*)d_in[7];
    const float* b4  = (const float*)d_in[8];
    const float* W5  = (const float*)d_in[9];
    const float* b5  = (const float*)d_in[10];
    const float* Wa  = (const float*)d_in[11];
    const float* ba  = (const float*)d_in[12];
    const float* Wo  = (const float*)d_in[13];
    const float* bo  = (const float*)d_in[14];

    unsigned short* ws = (unsigned short*)d_ws;

    pack_weights<<<dim3(20), dim3(256), 0, stream>>>(W2, W3, ws);
    feat3d_front<<<dim3(NCLUST), dim3(256), 0, stream>>>(
        xyz, W1, b1, b2, b3, ws, ws + WS_V, (float*)d_out);
    feat3d_tail<<<dim3(NCLUST/TCL), dim3(256), 0, stream>>>(
        ws + WS_V, W4, b4, W5, b5, Wa, ba, Wo, bo, (float*)d_out);
}

// Round 22
// 127.525 us; speedup vs baseline: 1.0551x; 1.0264x over previous
//
#include <hip/hip_runtime.h>
#include <math.h>

// Shapes fixed by setup_inputs(): B=8, N=8192, M=512 clusters, S=64 samples.
#define BB 8
#define NN 8192
#define MM 512
#define SS 64
#define NCLUST (BB*MM)                 // 4096
#define TCL 4                          // clusters per tail block

// d_out layout (flat, return order, all read back as f32):
// new_xyz[8*512*3] | idx(as float)[8*512*64] | attention[8*512] | orientation[8*512]
#define OUT_IDX   (BB*MM*3)            // 12288
#define OUT_ATT   (OUT_IDX + BB*MM*SS) // 274432
#define OUT_ORI   (OUT_ATT + BB*MM)    // 278528

// d_ws layout (ushorts): [0,8192) W2 B-frags | [8192,40960) W3 B-frags |
// [40960, 40960+4096*256) pooled v (bf16). ~2.08 MB.
#define WS_W3 8192
#define WS_V  40960

typedef short v8s __attribute__((ext_vector_type(8)));   // 8 bf16 (MFMA A/B frag)
typedef float v4f __attribute__((ext_vector_type(4)));   // MFMA C/D frag

static __device__ __forceinline__ unsigned short f2bf(float x) {
    unsigned int u = __float_as_uint(x);
    u += 0x7FFFu + ((u >> 16) & 1u);     // round-to-nearest-even
    return (unsigned short)(u >> 16);
}

// ---- Kernel 0: pack W2 (64x128) and W3 (128x256) fp32 -> bf16 MFMA B-frag
// layout. B-frag lane l holds B[kt*32+(l>>4)*8+j][nt*16+(l&15)], j=0..7,
// stored contiguous (16 B/lane) so the main kernel loads one dwordx4/frag.
__global__ void pack_weights(const float* __restrict__ W2,
                             const float* __restrict__ W3,
                             unsigned short* __restrict__ ws)
{
    const int gid = blockIdx.x * 256 + threadIdx.x;    // 0..5119
    const float* W; unsigned short* dst; int N, kt, nt, lane;
    if (gid < 1024) {                   // W2: 16 tiles * 64 lanes
        W = W2; N = 128;
        const int tile = gid >> 6; lane = gid & 63;
        kt = tile >> 3; nt = tile & 7;
        dst = ws + (size_t)(tile * 64 + lane) * 8;
    } else {                            // W3: 64 tiles * 64 lanes
        const int g = gid - 1024;
        W = W3; N = 256;
        const int tile = g >> 6; lane = g & 63;
        kt = tile >> 4; nt = tile & 15;
        dst = ws + WS_W3 + (size_t)(tile * 64 + lane) * 8;
    }
    const int k0 = kt * 32 + (lane >> 4) * 8;
    const int n  = nt * 16 + (lane & 15);
    union { unsigned short u[8]; v8s v; } f;
    #pragma unroll
    for (int j = 0; j < 8; ++j) f.u[j] = f2bf(W[(k0 + j) * N + n]);
    *(v8s*)dst = f.v;
}

// ---- Front (R20 base, <40.2us). R21 delta: pad pass + 1 barrier removed —
// reads clamp slot to (s < cnt ? s : 0). Slot 0 IS the TF pad value
// (globally first valid); cnt>=1 always (the center itself passes d2<4).
// Tested ALONE this time (R17 confounded it with setprio, which T5/m190
// says is null-to-negative on lockstep barrier-synced structures). ----
__global__ __launch_bounds__(256, 4) void feat3d_front(
    const float* __restrict__ xyz,
    const float* __restrict__ W1, const float* __restrict__ b1,
    const float* __restrict__ b2, const float* __restrict__ b3,
    const unsigned short* __restrict__ Wp,
    unsigned short* __restrict__ vdst,
    float* __restrict__ out)
{
    // LDS map: [0,8192) a2p | [8192,24576) a3p.
    //   smallf/ls_idx/ls_mask alias a3p[0..2368): all dead before the L2
    //   epilogue writes a3p (last reads happen before the L1-end sync).
    __shared__ __align__(16) unsigned char lds[24576];
    unsigned short* a2p = (unsigned short*)lds;            // h1 A-frags, 8 KB
    unsigned short* a3p = (unsigned short*)(lds + 8192);   // h2 A-frags, 16 KB
    float* smallf       = (float*)(lds + 8192);            // 512 f32: g | w1
    int* ls_idx         = (int*)(lds + 10240);             // 64
    unsigned long long* ls_mask = (unsigned long long*)(lds + 10496); // [2][4]

    float* ls_g  = smallf;         // [64][4]
    float* ls_w1 = smallf + 256;   // [64][4]

    const int t   = threadIdx.x;
    const int wv  = t >> 6;
    const int l   = t & 63;
    const int q   = l >> 4;
    const int r16 = l & 15;
    const int blk = blockIdx.x;
    const int b   = blk >> 9;
    const int m   = blk & 511;
    const float* xb = xyz + (size_t)b * (NN * 3);

    // Prefetch W2 B-frags NOW (packed, one dwordx4 each); they stay in flight
    // through the ball query (reg loads aren't drained by __syncthreads).
    const v8s* W2f = (const v8s*)Wp;
    v8s bfr[2][2];
    #pragma unroll
    for (int kt = 0; kt < 2; ++kt)
        #pragma unroll
        for (int ni = 0; ni < 2; ++ni)
            bfr[kt][ni] = W2f[(kt*8 + 2*wv + ni)*64 + l];

    const float cx = xb[m*3+0], cy = xb[m*3+1], cz = xb[m*3+2];

    if (t < 3) out[(b*MM + m)*3 + t] = xb[m*3 + t];   // new_xyz

    // Stage W1^T + b1 early (overlaps BQ latency).
    if (t < 64) {
        ls_w1[t*4+0] = W1[t];
        ls_w1[t*4+1] = W1[64 + t];
        ls_w1[t*4+2] = W1[128 + t];
        ls_w1[t*4+3] = b1[t];
    }

    // ---- Ball query with fused gather (256 pts/iter): first 64 idx with
    // d2 < 4.0 (by index); valid lane already holds dx,dy,dz so g is written
    // during the scan. ----
    int cnt = 0;
    {
        int base = 0, pb = 0;
        while (base < NN && cnt < SS) {
            const int j = base + t;
            const float dx = xb[j*3+0] - cx;
            const float dy = xb[j*3+1] - cy;
            const float dz = xb[j*3+2] - cz;
            // no fma contraction: idx must be exact at the d2==4.0 boundary
            const float d2 = __fadd_rn(__fadd_rn(__fmul_rn(dx,dx), __fmul_rn(dy,dy)),
                                       __fmul_rn(dz,dz));
            const bool valid = d2 < 4.0f;
            const unsigned long long mask = __ballot(valid);
            if (l == 0) ls_mask[pb*4 + wv] = mask;
            __syncthreads();
            const unsigned long long m0 = ls_mask[pb*4+0], m1 = ls_mask[pb*4+1],
                                     m2 = ls_mask[pb*4+2], m3 = ls_mask[pb*4+3];
            int below = __popcll(mask & ((1ull << l) - 1ull));
            if (wv > 0) below += (int)__popcll(m0);
            if (wv > 1) below += (int)__popcll(m1);
            if (wv > 2) below += (int)__popcll(m2);
            const int pos = cnt + below;
            if (valid && pos < SS) {
                ls_idx[pos]   = j;
                ls_g[pos*4+0] = dx * 0.5f;
                ls_g[pos*4+1] = dy * 0.5f;
                ls_g[pos*4+2] = dz * 0.5f;
            }
            cnt += (int)(__popcll(m0) + __popcll(m1) + __popcll(m2) + __popcll(m3));
            if (cnt > SS) cnt = SS;
            base += 256;
            pb ^= 1;               // double-buffered masks
        }
    }
    __syncthreads();   // ls_idx/ls_g[0..cnt) visible; cnt is block-uniform

    // Pad-free: slot select clamps to 0 (= globally first valid = TF pad).
    if (t < 64) out[OUT_IDX + (b*MM + m)*SS + t] = (float)ls_idx[(t < cnt) ? t : 0];

    // ---- L1 (fp32) + pack h1 into A-frag layout:
    // lane l of wave wv produces s = wv*16+r16, c = kt*32+q*8+j ----
    {
        const int s = wv*16 + r16;
        const int sel = (s < cnt) ? s : 0;          // pad via clamped read
        const float4 g4 = *(const float4*)&ls_g[sel*4];
        #pragma unroll
        for (int kt = 0; kt < 2; ++kt) {
            union { unsigned short u[8]; v8s v; } fr;
            #pragma unroll
            for (int j = 0; j < 8; ++j) {
                const int c = kt*32 + q*8 + j;
                const float4 w = *(const float4*)&ls_w1[c*4];
                const float h = fmaf(g4.x, w.x, fmaf(g4.y, w.y, fmaf(g4.z, w.z, w.w)));
                fr.u[j] = f2bf(fmaxf(h, 0.f));
            }
            *(v8s*)&a2p[((kt*4 + wv)*64 + l)*8] = fr.v;
        }
    }
    __syncthreads();

    // ---- L2 MFMA: h2 = relu(h1 @ W2 + b2). Wave wv owns nt {2wv, 2wv+1}. ----
    {
        const v4f z = {0.f, 0.f, 0.f, 0.f};
        v4f acc[4][2];
        #pragma unroll
        for (int mt = 0; mt < 4; ++mt) { acc[mt][0] = z; acc[mt][1] = z; }

        #pragma unroll
        for (int kt = 0; kt < 2; ++kt)
            #pragma unroll
            for (int mt = 0; mt < 4; ++mt) {
                const v8s a = *(const v8s*)&a2p[((kt*4 + mt)*64 + l)*8];
                #pragma unroll
                for (int ni = 0; ni < 2; ++ni)
                    acc[mt][ni] = __builtin_amdgcn_mfma_f32_16x16x32_bf16(
                        a, bfr[kt][ni], acc[mt][ni], 0, 0, 0);
            }

        // Epilogue: +b2, relu, bf16, scatter into L3 A-frag layout.
        // C/D elem (mt,ni,rg): s = mt*16+q*4+rg, c2 = (2wv+ni)*16+r16.
        #pragma unroll
        for (int ni = 0; ni < 2; ++ni) {
            const int c2  = (2*wv + ni)*16 + r16;
            const float bias = b2[c2];
            const int kt3 = c2 >> 5;
            const int lhi = ((c2 >> 3) & 3) << 4;
            const int j3  = c2 & 7;
            #pragma unroll
            for (int mt = 0; mt < 4; ++mt)
                #pragma unroll
                for (int rg = 0; rg < 4; ++rg) {
                    const float h = fmaxf(acc[mt][ni][rg] + bias, 0.f);
                    const int s15 = q*4 + rg;
                    a3p[((kt3*4 + mt)*64 + (lhi | s15))*8 + j3] = f2bf(h);
                }
        }
    }
    __syncthreads();

    // ---- L3 MFMA in 2 passes; pool in regs; v -> global bf16. ----
    {
        const v8s* W3f = (const v8s*)(Wp + WS_W3);
        unsigned short* vrow = vdst + (size_t)blk * 256;

        #pragma unroll
        for (int np = 0; np < 2; ++np) {
            const int nt0 = 4*wv + 2*np;
            const v4f z = {0.f, 0.f, 0.f, 0.f};
            v4f acc[4][2];
            #pragma unroll
            for (int mt = 0; mt < 4; ++mt) { acc[mt][0] = z; acc[mt][1] = z; }

            v8s bb0 = W3f[(0*16 + nt0    )*64 + l];
            v8s bb1 = W3f[(0*16 + nt0 + 1)*64 + l];
            #pragma unroll
            for (int kt = 0; kt < 4; ++kt) {
                v8s a[4];
                #pragma unroll
                for (int mt = 0; mt < 4; ++mt)
                    a[mt] = *(const v8s*)&a3p[((kt*4 + mt)*64 + l)*8];
                v8s nb0, nb1;
                if (kt < 3) {
                    nb0 = W3f[((kt+1)*16 + nt0    )*64 + l];
                    nb1 = W3f[((kt+1)*16 + nt0 + 1)*64 + l];
                }
                #pragma unroll
                for (int mt = 0; mt < 4; ++mt) {
                    acc[mt][0] = __builtin_amdgcn_mfma_f32_16x16x32_bf16(
                        a[mt], bb0, acc[mt][0], 0, 0, 0);
                    acc[mt][1] = __builtin_amdgcn_mfma_f32_16x16x32_bf16(
                        a[mt], bb1, acc[mt][1], 0, 0, 0);
                }
                if (kt < 3) { bb0 = nb0; bb1 = nb1; }
            }

            // Pool over s (16 regs + cross-quad shfl); bias+relu after pool
            // (relu monotone, bias per-column => commutes). Store bf16 v.
            #pragma unroll
            for (int ni = 0; ni < 2; ++ni) {
                float mx = acc[0][ni][0];
                #pragma unroll
                for (int mt = 0; mt < 4; ++mt)
                    #pragma unroll
                    for (int rg = 0; rg < 4; ++rg)
                        mx = fmaxf(mx, acc[mt][ni][rg]);
                mx = fmaxf(mx, __shfl_xor(mx, 16));
                mx = fmaxf(mx, __shfl_xor(mx, 32));
                if (q == 0) {
                    const int c = (nt0 + ni)*16 + r16;
                    vrow[c] = f2bf(fmaxf(mx + b3[c], 0.f));
                }
            }
        }
    }
}

// ---- Tail (R20, unchanged): 4 clusters/block, grid 1024 (4 blocks/CU).
// W4/W5 streamed once per block, 16 fma per loaded W4 float4. ----
__global__ __launch_bounds__(256) void feat3d_tail(
    const unsigned short* __restrict__ vsrc,
    const float* __restrict__ W4, const float* __restrict__ b4,
    const float* __restrict__ W5, const float* __restrict__ b5,
    const float* __restrict__ Wa, const float* __restrict__ ba,
    const float* __restrict__ Wo, const float* __restrict__ bo,
    float* __restrict__ out)
{
    __shared__ __align__(16) float V[TCL*256];        // 4 KB (flat [cl*256+k])
    __shared__ __align__(16) float h4part[8][TCL*128];// 16 KB
    __shared__ __align__(16) float h4f[TCL*128];      // 2 KB
    __shared__ __align__(16) float h5p[4][TCL*64];    // 4 KB

    const int t   = threadIdx.x;
    const int cl0 = blockIdx.x * TCL;

    // Load v tile (bf16 -> f32): 2048 bf16 = 4 KB; one uint4 (8 bf16)/thread.
    {
        const uint4 r = ((const uint4*)(vsrc + (size_t)cl0 * 256))[t];
        const unsigned int u[4] = {r.x, r.y, r.z, r.w};
        #pragma unroll
        for (int j = 0; j < 4; ++j) {
            V[t*8 + 2*j]     = __uint_as_float(u[j] << 16);
            V[t*8 + 2*j + 1] = __uint_as_float(u[j] & 0xFFFF0000u);
        }
    }
    __syncthreads();

    // L4: thread = (cgp = t&31 -> 4 cols, kp = t>>5 -> 32 ks). W4 float4
    // loaded once, fma'd into 4 named cluster accs (16 fma/load).
    {
        const int cgp = t & 31;
        const int kp  = t >> 5;
        const float4* W4v = (const float4*)W4;   // row-major [256][32] float4
        float4 a0 = make_float4(0.f,0.f,0.f,0.f);
        float4 a1 = make_float4(0.f,0.f,0.f,0.f);
        float4 a2 = make_float4(0.f,0.f,0.f,0.f);
        float4 a3 = make_float4(0.f,0.f,0.f,0.f);
        const int kbase = kp * 32;
        #pragma unroll 4
        for (int kk = 0; kk < 32; ++kk) {
            const int k = kbase + kk;
            const float4 w = W4v[k*32 + cgp];
            const float v0 = V[0*256 + k];
            const float v1 = V[1*256 + k];
            const float v2 = V[2*256 + k];
            const float v3 = V[3*256 + k];
            a0.x = fmaf(v0, w.x, a0.x); a0.y = fmaf(v0, w.y, a0.y);
            a0.z = fmaf(v0, w.z, a0.z); a0.w = fmaf(v0, w.w, a0.w);
            a1.x = fmaf(v1, w.x, a1.x); a1.y = fmaf(v1, w.y, a1.y);
            a1.z = fmaf(v1, w.z, a1.z); a1.w = fmaf(v1, w.w, a1.w);
            a2.x = fmaf(v2, w.x, a2.x); a2.y = fmaf(v2, w.y, a2.y);
            a2.z = fmaf(v2, w.z, a2.z); a2.w = fmaf(v2, w.w, a2.w);
            a3.x = fmaf(v3, w.x, a3.x); a3.y = fmaf(v3, w.y, a3.y);
            a3.z = fmaf(v3, w.z, a3.z); a3.w = fmaf(v3, w.w, a3.w);
        }
        *(float4*)&h4part[kp][0*128 + cgp*4] = a0;
        *(float4*)&h4part[kp][1*128 + cgp*4] = a1;
        *(float4*)&h4part[kp][2*128 + cgp*4] = a2;
        *(float4*)&h4part[kp][3*128 + cgp*4] = a3;
    }
    __syncthreads();

    // Reduce 8 k-partials -> h4f[cl*128+c] (+b4). 512 outputs, 2/thread.
    #pragma unroll
    for (int idx = t; idx < TCL*128; idx += 256) {
        const int c = idx & 127;
        float s = b4[c];
        #pragma unroll
        for (int kp = 0; kp < 8; ++kp) s += h4part[kp][idx];
        h4f[idx] = s;
    }
    __syncthreads();

    // L5: thread = (c5 = t&63, kq = t>>6); W5 loaded once, 4 named accs.
    {
        const int c5 = t & 63;
        const int kq = t >> 6;
        float s0 = 0.f, s1 = 0.f, s2 = 0.f, s3 = 0.f;
        #pragma unroll 4
        for (int kk = 0; kk < 32; ++kk) {
            const int k = kq*32 + kk;
            const float w = W5[k*64 + c5];
            s0 = fmaf(h4f[0*128 + k], w, s0);
            s1 = fmaf(h4f[1*128 + k], w, s1);
            s2 = fmaf(h4f[2*128 + k], w, s2);
            s3 = fmaf(h4f[3*128 + k], w, s3);
        }
        h5p[kq][0*64 + c5] = s0;
        h5p[kq][1*64 + c5] = s1;
        h5p[kq][2*64 + c5] = s2;
        h5p[kq][3*64 + c5] = s3;
    }
    __syncthreads();

    // Heads: wave wv owns cluster wv. attention = softplus(h5.Wa+ba);
    // orientation = atan2(o1,o0) (normalization scale-invariant -> skipped).
    {
        const int wv = t >> 6, l = t & 63;
        float h5v = b5[l];
        #pragma unroll
        for (int kq = 0; kq < 4; ++kq) h5v += h5p[kq][wv*64 + l];
        float va = h5v * Wa[l];
        float v0 = h5v * Wo[2*l + 0];
        float v1 = h5v * Wo[2*l + 1];
        #pragma unroll
        for (int off = 32; off > 0; off >>= 1) {
            va += __shfl_down(va, off);
            v0 += __shfl_down(v0, off);
            v1 += __shfl_down(v1, off);
        }
        if (l == 0) {
            const int cg = cl0 + wv;
            const float a = va + ba[0];
            out[OUT_ATT + cg] = fmaxf(a, 0.f) + log1pf(expf(-fabsf(a)));
            out[OUT_ORI + cg] = atan2f(v1 + bo[1], v0 + bo[0]);
        }
    }
}

extern "C" void kernel_launch(void* const* d_in, const int* in_sizes, int n_in,
                              void* d_out, int out_size, void* d_ws, size_t ws_size,
                              hipStream_t stream) {
    const float* xyz = (const float*)d_in[0];
    const float* W1  = (const float*)d_in[1];
    const float* b1  = (const float*)d_in[2];
    const float* W2  = (const float*)d_in[3];
    const float* b2  = (const float*)d_in[4];
    const float* W3  = (const float*)d_in[5];
    const float* b3  = (const float*)d_in[6];
    const float* W4  = (const float*)d_in[7];
    const float* b4  = (const float*)d_in[8];
    const float* W5  = (const float*)d_in[9];
    const float* b5  = (const float*)d_in[10];
    const float* Wa  = (const float*)d_in[11];
    const float* ba  = (const float*)d_in[12];
    const float* Wo  = (const float*)d_in[13];
    const float* bo  = (const float*)d_in[14];

    unsigned short* ws = (unsigned short*)d_ws;

    pack_weights<<<dim3(20), dim3(256), 0, stream>>>(W2, W3, ws);
    feat3d_front<<<dim3(NCLUST), dim3(256), 0, stream>>>(
        xyz, W1, b1, b2, b3, ws, ws + WS_V, (float*)d_out);
    feat3d_tail<<<dim3(NCLUST/TCL), dim3(256), 0, stream>>>(
        ws + WS_V, W4, b4, W5, b5, Wa, ba, Wo, bo, (float*)d_out);
}